// Round 11
// baseline (196.310 us; speedup 1.0000x reference)
//
#include <hip/hip_runtime.h>
#include <math.h>

#define BATCH 8192
typedef unsigned short u16;
typedef unsigned int u32;
typedef __attribute__((ext_vector_type(8))) short bf16x8;
typedef __attribute__((ext_vector_type(4))) float f32x4;
typedef __attribute__((ext_vector_type(4))) unsigned short u16x4;

__device__ __forceinline__ float sigm(float v) { return 1.0f / (1.0f + __expf(-v)); }
__device__ __forceinline__ u16 f2bf(float f) {
    union { float f; u32 u; } v; v.f = f;
    u32 r = v.u + 0x7FFFu + ((v.u >> 16) & 1u);   // RNE
    return (u16)(r >> 16);
}
__device__ __forceinline__ float bf2f(u16 h) {
    union { u32 u; float f; } v; v.u = ((u32)h) << 16; return v.f;
}
__device__ __forceinline__ void split_store4(float4 v, u16* hp, u16* lp) {
    u16 h0 = f2bf(v.x), h1 = f2bf(v.y), h2 = f2bf(v.z), h3 = f2bf(v.w);
    u16x4 hv = {h0, h1, h2, h3};
    u16x4 lv = {f2bf(v.x - bf2f(h0)), f2bf(v.y - bf2f(h1)),
                f2bf(v.z - bf2f(h2)), f2bf(v.w - bf2f(h3))};
    *(u16x4*)hp = hv; *(u16x4*)lp = lv;
}
// fragment-linear B: element [(nt*nch + ch)*64 + lane]*8 + e  ==  B[nt*16+(lane&15)][ch*32+(lane>>4)*8+e]
__device__ __forceinline__ bf16x8 bfrag(const u16* Bf, int nt, int ch, int nch, int lane) {
    return *(const bf16x8*)(Bf + (((size_t)nt * nch + ch) * 64 + lane) * 8);
}
#define MFMA(a, b, c) __builtin_amdgcn_mfma_f32_16x16x32_bf16(a, b, c, 0, 0, 0)

// ---------------- workspace layout (u16 elements); hi plane then lo plane ----------------
#define S_FBT 69632   // [17 nt][8 ch] frag-linear, n<272, k<256
#define S_B1  61440   // 3 taps x [8 nt][5 ch], n<128, k<160 (k>=129 zero)
#define S_B2A 16384   // [4 nt][8 ch]
#define S_B2B 24576   // [4 nt][12 ch]
#define S_B3  8192    // [4 nt][4 ch]
#define S_B4  8192    // [8 nt][2 ch]
#define S_BL  131072  // [32 nt][8 ch]  n = gate*128+j, k: 0..127 W / 128..255 U
#define P_FBT 0
#define P_B1  139264
#define P_B2A 262144
#define P_B2B 294912
#define P_B3  344064
#define P_B4  360448
#define P_BL  376832
#define N_PREP 319488

// ---------------- k_prep: build fragment-linear split-bf16 B planes ----------------
__global__ __launch_bounds__(256) void k_prep(const float* __restrict__ fb,
                                              const float* __restrict__ w1, const float* __restrict__ w2,
                                              const float* __restrict__ w3, const float* __restrict__ w4,
                                              const float* __restrict__ wi, const float* __restrict__ wf,
                                              const float* __restrict__ wg, const float* __restrict__ wo,
                                              const float* __restrict__ ui, const float* __restrict__ uf,
                                              const float* __restrict__ ug, const float* __restrict__ uo,
                                              u16* __restrict__ wsu) {
    const float* Ws[8] = {wi, wf, wg, wo, ui, uf, ug, uo};
    for (int i = blockIdx.x * 256 + threadIdx.x; i < N_PREP; i += gridDim.x * 256) {
        int r = i;
        float v; int P, S, idx;
        if (r < S_FBT) {                                    // FBT nch=8
            int f = r >> 9, lane = (r & 511) >> 3, e = r & 7;
            int n = (f >> 3) * 16 + (lane & 15), k = (f & 7) * 32 + (lane >> 4) * 8 + e;
            int c = n >> 1, part = n & 1;
            v = (n < 258) ? fb[(size_t)(c + part * 129) * 256 + k] : 0.f;
            P = P_FBT; S = S_FBT; idx = r;
        } else if ((r -= S_FBT) < S_B1) {                   // B1: 3 taps, nch=5
            int kk = r / 20480, r2 = r - kk * 20480;
            int f = r2 >> 9, lane = (r2 & 511) >> 3, e = r2 & 7;
            int n = (f / 5) * 16 + (lane & 15), k = (f % 5) * 32 + (lane >> 4) * 8 + e;
            v = (k < 129) ? w1[(size_t)n * 387 + k * 3 + kk] : 0.f;
            P = P_B1; S = S_B1; idx = r;
        } else if ((r -= S_B1) < S_B2A) {                   // B2A nch=8
            int f = r >> 9, lane = (r & 511) >> 3, e = r & 7;
            int n = (f >> 3) * 16 + (lane & 15), k = (f & 7) * 32 + (lane >> 4) * 8 + e;
            v = w2[(size_t)n * 384 + (k & 127) * 3 + (k >> 7) + 1];
            P = P_B2A; S = S_B2A; idx = r;
        } else if ((r -= S_B2A) < S_B2B) {                  // B2B nch=12
            int f = r >> 9, lane = (r & 511) >> 3, e = r & 7;
            int n = (f / 12) * 16 + (lane & 15), k = (f % 12) * 32 + (lane >> 4) * 8 + e;
            v = w2[(size_t)n * 384 + (k & 127) * 3 + (k >> 7)];
            P = P_B2B; S = S_B2B; idx = r;
        } else if ((r -= S_B2B) < S_B3) {                   // B3 nch=4
            int f = r >> 9, lane = (r & 511) >> 3, e = r & 7;
            int n = (f >> 2) * 16 + (lane & 15), k = (f & 3) * 32 + (lane >> 4) * 8 + e;
            v = w3[(size_t)n * 192 + (k & 63) * 3 + (k >> 6) + 1];
            P = P_B3; S = S_B3; idx = r;
        } else if ((r -= S_B3) < S_B4) {                    // B4 nch=2
            int f = r >> 9, lane = (r & 511) >> 3, e = r & 7;
            int n = (f >> 1) * 16 + (lane & 15), k = (f & 1) * 32 + (lane >> 4) * 8 + e;
            v = w4[(size_t)n * 192 + k * 3 + 1];
            P = P_B4; S = S_B4; idx = r;
        } else {                                            // BL nch=8
            r -= S_B4;
            int f = r >> 9, lane = (r & 511) >> 3, e = r & 7;
            int n = (f >> 3) * 16 + (lane & 15), k = (f & 7) * 32 + (lane >> 4) * 8 + e;
            int g = n >> 7, j = n & 127;
            v = Ws[g + ((k >= 128) ? 4 : 0)][(size_t)j * 128 + (k & 127)];
            P = P_BL; S = S_BL; idx = r;
        }
        u16 h = f2bf(v);
        wsu[P + idx] = h;
        wsu[P + S + idx] = f2bf(v - bf2f(h));
    }
}

// ---------------- k_all: STFT -> mag -> enc1 -> enc2 -> enc3 -> enc4 -> LSTM -> head ----------------
// block 512 (8 waves), 16 batches (64 stft rows, mt=4), grid 512 (= 2 blocks/CU).
// LDS union (u16), time-multiplexed (R9 layout, known-good):
//   phase A: audio  aAh[0,11520) aAl[11520,23040)   stride 720 (conflict-free)
//   phase B: mag    mAh[0,16128) mAl[16128,32256)   rows bb*6+tp, stride 168 (zero-passed)
//   phase C: e1     eAh[0,8320)  eAl[8320,16640)    rows=batch, stride 520
//            s2 [16640,20992) s3 [20992,23296) xh [23296,31744) pr [31744,32256)
__global__ __launch_bounds__(512) void k_all(const float* __restrict__ audio,
                                             const u16* __restrict__ wsu,
                                             const float* __restrict__ hin, const float* __restrict__ cin,
                                             const float* __restrict__ b1, const float* __restrict__ b2,
                                             const float* __restrict__ b3, const float* __restrict__ b4,
                                             const float* __restrict__ bxi, const float* __restrict__ bxf,
                                             const float* __restrict__ bxg, const float* __restrict__ bxo,
                                             const float* __restrict__ bhi, const float* __restrict__ bhf,
                                             const float* __restrict__ bhg, const float* __restrict__ bho,
                                             const float* __restrict__ cw, const float* __restrict__ cb,
                                             float* __restrict__ out) {
    __shared__ __align__(16) u16 uni[32256];
    u16* aAh = uni;
    u16* aAl = uni + 11520;
    u16* mAh = uni;
    u16* mAl = uni + 16128;
    u16* eAh = uni;
    u16* eAl = uni + 8320;
    u16* s2h = uni + 16640;
    u16* s2l = uni + 18816;
    u16* s3h = uni + 20992;
    u16* s3l = uni + 22144;
    u16* xhh = uni + 23296;
    u16* xhl = uni + 27520;
    float* pr = (float*)(uni + 31744);
    const int tid = threadIdx.x;
    const int b0 = blockIdx.x << 4;
    const int lane = tid & 63, w = tid >> 6;
    const int m = lane & 15, quad = lane >> 4;
    // ---- phase A: stage audio (split bf16, reflect pad) ----
    for (int i = tid; i < 16 * 160; i += 512) {
        int bb = i / 160, j4 = (i - bb * 160) * 4;
        const float* ap = audio + (size_t)(b0 + bb) * 576;
        float4 v;
        if (j4 < 576) v = *(const float4*)(ap + j4);
        else { v.x = ap[1150 - j4]; v.y = ap[1149 - j4]; v.z = ap[1148 - j4]; v.w = ap[1147 - j4]; }
        int phys = bb * 720 + j4 + (j4 >> 7) * 8;
        split_store4(v, aAh + phys, aAl + phys);
    }
    // ---- early scalar loads for LSTM epilogue (registers only; overlap with GEMM phases) ----
    const int j = w * 16 + m;
    const float bi = bxi[j] + bhi[j];
    const float bff = bxf[j] + bhf[j];
    const float bgg = bxg[j] + bhg[j];
    const float boo = bxo[j] + bho[j];
    const float cwj = cw[j];
    const float cbv = cb[0];
    float civ[4];
    #pragma unroll
    for (int r = 0; r < 4; ++r)
        civ[r] = cin[(size_t)(b0 + quad * 4 + r) * 128 + j];
    __syncthreads();
    // ---- GEMM1 (STFT): wave w owns nt = 2w..2w+1 (w==7 also nt=16), mt=4 ----
    const u16* fbT = wsu + P_FBT;
    const int tcnt = (w == 7) ? 3 : 2;
    f32x4 acc[4][3];
    #pragma unroll
    for (int mt = 0; mt < 4; ++mt)
        #pragma unroll
        for (int t = 0; t < 3; ++t) acc[mt][t] = (f32x4){0.f, 0.f, 0.f, 0.f};
    for (int ch = 0; ch < 8; ++ch) {
        bf16x8 ah[4], al[4];
        #pragma unroll
        for (int mt = 0; mt < 4; ++mt) {
            int Rm = mt * 16 + m;
            int phys = (Rm >> 2) * 720 + (Rm & 3) * 136 + ch * 32 + quad * 8 + ((ch >= 4) ? 8 : 0);
            ah[mt] = *(const bf16x8*)(aAh + phys);
            al[mt] = *(const bf16x8*)(aAl + phys);
        }
        #pragma unroll
        for (int tt = 0; tt < 3; ++tt) {
            if (tt < tcnt) {
                int t = w * 2 + tt;
                bf16x8 bh = bfrag(fbT, t, ch, 8, lane);
                bf16x8 bl_ = bfrag(fbT + S_FBT, t, ch, 8, lane);
                #pragma unroll
                for (int mt = 0; mt < 4; ++mt) {
                    acc[mt][tt] = MFMA(ah[mt], bh, acc[mt][tt]);
                    acc[mt][tt] = MFMA(ah[mt], bl_, acc[mt][tt]);
                    acc[mt][tt] = MFMA(al[mt], bh, acc[mt][tt]);
                }
            }
        }
    }
    __syncthreads();                                // audio dead
    for (int i = tid; i < 16128; i += 512) ((u32*)uni)[i] = 0u;   // zero union (mag pads)
    __syncthreads();
    // ---- magnitude epilogue -> mag LDS (6-row layout, boundary rows stay zero) ----
    #pragma unroll
    for (int tt = 0; tt < 3; ++tt) {
        if (tt < tcnt) {
            int n = (w * 2 + tt) * 16 + m;
            #pragma unroll
            for (int mt = 0; mt < 4; ++mt)
                #pragma unroll
                for (int r = 0; r < 4; ++r) {
                    float vv = acc[mt][tt][r];
                    float s = vv * vv;
                    s += __shfl_xor(s, 1);
                    if (!(n & 1)) {
                        int R = mt * 16 + quad * 4 + r;
                        int bb = R >> 2, t = R & 3, c = n >> 1;
                        float sv = sqrtf(s);
                        u16 h = f2bf(sv);
                        int phys = (bb * 6 + t + 1) * 168 + c;
                        mAh[phys] = h;
                        mAl[phys] = f2bf(sv - bf2f(h));
                    }
                }
        }
    }
    __syncthreads();
    // ---- GEMM2 (enc1): wave w owns nt = w (N=128), mt=4, K = 3 taps x 5 ch ----
    const u16* B1h = wsu + P_B1;
    const u16* B1l = wsu + P_B1 + S_B1;
    f32x4 acc2[4];
    #pragma unroll
    for (int mt = 0; mt < 4; ++mt) acc2[mt] = (f32x4){0.f, 0.f, 0.f, 0.f};
    #pragma unroll
    for (int kk = 0; kk < 3; ++kk) {
        #pragma unroll
        for (int ch = 0; ch < 5; ++ch) {
            bf16x8 bh = bfrag(B1h + kk * 20480, w, ch, 5, lane);
            bf16x8 bl_ = bfrag(B1l + kk * 20480, w, ch, 5, lane);
            #pragma unroll
            for (int mt = 0; mt < 4; ++mt) {
                int Rm = mt * 16 + m;
                int phys = ((Rm >> 2) * 6 + (Rm & 3) + kk) * 168 + ch * 32 + quad * 8;
                bf16x8 ah = *(const bf16x8*)(mAh + phys);
                bf16x8 al = *(const bf16x8*)(mAl + phys);
                acc2[mt] = MFMA(ah, bh, acc2[mt]);
                acc2[mt] = MFMA(ah, bl_, acc2[mt]);
                acc2[mt] = MFMA(al, bh, acc2[mt]);
            }
        }
    }
    __syncthreads();                                // mag dead
    // ---- e1 -> LDS (split), h -> xh cols 128..255 ----
    {
        int n = w * 16 + m;
        float bv = b1[n];
        #pragma unroll
        for (int mt = 0; mt < 4; ++mt)
            #pragma unroll
            for (int r = 0; r < 4; ++r) {
                int R = mt * 16 + quad * 4 + r;
                float vv = fmaxf(acc2[mt][r] + bv, 0.f);
                u16 h = f2bf(vv);
                int phys = (R >> 2) * 520 + (R & 3) * 128 + n;
                eAh[phys] = h;
                eAl[phys] = f2bf(vv - bf2f(h));
            }
    }
    for (int i = tid; i < 16 * 32; i += 512) {
        int row = i >> 5, c4 = (i & 31) * 4;
        float4 v = *(const float4*)(hin + (size_t)(b0 + row) * 128 + c4);
        split_store4(v, xhh + row * 264 + 128 + c4, xhl + row * 264 + 128 + c4);
    }
    __syncthreads();
    // ---- enc2: waves 0-3 = enc2a (K=256), waves 4-7 = enc2b (K=384) ----
    {
        const int isB = w >> 2, nt = w & 3;
        f32x4 a2 = (f32x4){0.f, 0.f, 0.f, 0.f};
        if (!isB) {
            const u16* Bh = wsu + P_B2A;
            const u16* Bl = Bh + S_B2A;
            #pragma unroll
            for (int ch = 0; ch < 8; ++ch) {
                int phys = m * 520 + ch * 32 + quad * 8;
                bf16x8 ah = *(const bf16x8*)(eAh + phys);
                bf16x8 al = *(const bf16x8*)(eAl + phys);
                bf16x8 bh = bfrag(Bh, nt, ch, 8, lane);
                bf16x8 bl_ = bfrag(Bl, nt, ch, 8, lane);
                a2 = MFMA(ah, bh, a2);
                a2 = MFMA(ah, bl_, a2);
                a2 = MFMA(al, bh, a2);
            }
        } else {
            const u16* Bh = wsu + P_B2B;
            const u16* Bl = Bh + S_B2B;
            #pragma unroll
            for (int ch = 0; ch < 12; ++ch) {
                int phys = m * 520 + 128 + ch * 32 + quad * 8;
                bf16x8 ah = *(const bf16x8*)(eAh + phys);
                bf16x8 al = *(const bf16x8*)(eAl + phys);
                bf16x8 bh = bfrag(Bh, nt, ch, 12, lane);
                bf16x8 bl_ = bfrag(Bl, nt, ch, 12, lane);
                a2 = MFMA(ah, bh, a2);
                a2 = MFMA(ah, bl_, a2);
                a2 = MFMA(al, bh, a2);
            }
        }
        const int oc = nt * 16 + m;
        const float bv = b2[oc];
        const int col = isB * 64 + oc;
        #pragma unroll
        for (int r = 0; r < 4; ++r) {
            int row = quad * 4 + r;
            float vv = fmaxf(a2[r] + bv, 0.f);
            u16 h = f2bf(vv);
            s2h[row * 136 + col] = h;
            s2l[row * 136 + col] = f2bf(vv - bf2f(h));
        }
    }
    __syncthreads();
    // ---- enc3: waves 0-3, K=128 (4 ch), N=64 ----
    if (w < 4) {
        const u16* Bh = wsu + P_B3;
        const u16* Bl = Bh + S_B3;
        f32x4 a3 = (f32x4){0.f, 0.f, 0.f, 0.f};
        #pragma unroll
        for (int ch = 0; ch < 4; ++ch) {
            int phys = m * 136 + ch * 32 + quad * 8;
            bf16x8 ah = *(const bf16x8*)(s2h + phys);
            bf16x8 al = *(const bf16x8*)(s2l + phys);
            bf16x8 bh = bfrag(Bh, w, ch, 4, lane);
            bf16x8 bl_ = bfrag(Bl, w, ch, 4, lane);
            a3 = MFMA(ah, bh, a3);
            a3 = MFMA(ah, bl_, a3);
            a3 = MFMA(al, bh, a3);
        }
        const int n = w * 16 + m;
        const float bv = b3[n];
        #pragma unroll
        for (int r = 0; r < 4; ++r) {
            int row = quad * 4 + r;
            float vv = fmaxf(a3[r] + bv, 0.f);
            u16 h = f2bf(vv);
            s3h[row * 72 + n] = h;
            s3l[row * 72 + n] = f2bf(vv - bf2f(h));
        }
    }
    __syncthreads();
    // ---- enc4: all 8 waves, K=64 (2 ch), N=128 -> x into xh cols 0..127 ----
    {
        const u16* Bh = wsu + P_B4;
        const u16* Bl = Bh + S_B4;
        f32x4 a4 = (f32x4){0.f, 0.f, 0.f, 0.f};
        #pragma unroll
        for (int ch = 0; ch < 2; ++ch) {
            int phys = m * 72 + ch * 32 + quad * 8;
            bf16x8 ah = *(const bf16x8*)(s3h + phys);
            bf16x8 al = *(const bf16x8*)(s3l + phys);
            bf16x8 bh = bfrag(Bh, w, ch, 2, lane);
            bf16x8 bl_ = bfrag(Bl, w, ch, 2, lane);
            a4 = MFMA(ah, bh, a4);
            a4 = MFMA(ah, bl_, a4);
            a4 = MFMA(al, bh, a4);
        }
        const int n = w * 16 + m;
        const float bv = b4[n];
        #pragma unroll
        for (int r = 0; r < 4; ++r) {
            int row = quad * 4 + r;
            float vv = fmaxf(a4[r] + bv, 0.f);
            u16 h = f2bf(vv);
            xhh[row * 264 + n] = h;
            xhl[row * 264 + n] = f2bf(vv - bf2f(h));
        }
    }
    __syncthreads();
    // ---- LSTM: wave w owns j-tile w x all 4 gates; K=256 (8 ch) ----
    {
        const u16* BLh = wsu + P_BL;
        const u16* BLl = BLh + S_BL;
        f32x4 ag[4];
        #pragma unroll
        for (int g = 0; g < 4; ++g) ag[g] = (f32x4){0.f, 0.f, 0.f, 0.f};
        #pragma unroll 4
        for (int ch = 0; ch < 8; ++ch) {
            int phys = m * 264 + ch * 32 + quad * 8;
            bf16x8 ah = *(const bf16x8*)(xhh + phys);
            bf16x8 al = *(const bf16x8*)(xhl + phys);
            #pragma unroll
            for (int g = 0; g < 4; ++g) {
                int nt = g * 8 + w;
                bf16x8 bh = bfrag(BLh, nt, ch, 8, lane);
                bf16x8 bl_ = bfrag(BLl, nt, ch, 8, lane);
                ag[g] = MFMA(ah, bh, ag[g]);
                ag[g] = MFMA(ah, bl_, ag[g]);
                ag[g] = MFMA(al, bh, ag[g]);
            }
        }
        float partial[4];
        #pragma unroll
        for (int r = 0; r < 4; ++r) {
            const int b = b0 + quad * 4 + r;
            const float ig = sigm(ag[0][r] + bi);
            const float fg = sigm(ag[1][r] + bff);
            const float gg = tanhf(ag[2][r] + bgg);
            const float og = sigm(ag[3][r] + boo);
            const float co = fg * civ[r] + ig * gg;
            const float ho = og * tanhf(co);
            out[(size_t)BATCH + (size_t)b * 128 + j] = ho;
            out[(size_t)BATCH + (size_t)BATCH * 128 + (size_t)b * 128 + j] = co;
            partial[r] = fmaxf(ho, 0.f) * cwj;
        }
        #pragma unroll
        for (int off = 1; off < 16; off <<= 1)
            #pragma unroll
            for (int r = 0; r < 4; ++r) partial[r] += __shfl_xor(partial[r], off);
        if (m == 0) {
            #pragma unroll
            for (int r = 0; r < 4; ++r) pr[w * 16 + quad * 4 + r] = partial[r];
        }
    }
    __syncthreads();
    if (tid < 16) {
        float s = cbv;
        #pragma unroll
        for (int g = 0; g < 8; ++g) s += pr[g * 16 + tid];
        out[b0 + tid] = sigm(s);
    }
}

extern "C" void kernel_launch(void* const* d_in, const int* in_sizes, int n_in,
                              void* d_out, int out_size, void* d_ws, size_t ws_size,
                              hipStream_t stream) {
    const float* audio = (const float*)d_in[0];
    const float* hin   = (const float*)d_in[1];
    const float* cin   = (const float*)d_in[2];
    const float* fb    = (const float*)d_in[3];
    const float* w1    = (const float*)d_in[4];
    const float* b1    = (const float*)d_in[5];
    const float* w2    = (const float*)d_in[6];
    const float* b2    = (const float*)d_in[7];
    const float* w3    = (const float*)d_in[8];
    const float* b3    = (const float*)d_in[9];
    const float* w4    = (const float*)d_in[10];
    const float* b4    = (const float*)d_in[11];
    const float* wi    = (const float*)d_in[12];
    const float* wf    = (const float*)d_in[13];
    const float* wg    = (const float*)d_in[14];
    const float* wo    = (const float*)d_in[15];
    const float* ui    = (const float*)d_in[16];
    const float* uf    = (const float*)d_in[17];
    const float* ug    = (const float*)d_in[18];
    const float* uo    = (const float*)d_in[19];
    const float* bxi   = (const float*)d_in[20];
    const float* bxf   = (const float*)d_in[21];
    const float* bxg   = (const float*)d_in[22];
    const float* bxo   = (const float*)d_in[23];
    const float* bhi   = (const float*)d_in[24];
    const float* bhf   = (const float*)d_in[25];
    const float* bhg   = (const float*)d_in[26];
    const float* bho   = (const float*)d_in[27];
    const float* cw    = (const float*)d_in[28];
    const float* cb    = (const float*)d_in[29];
    float* out = (float*)d_out;

    u16* wsu = (u16*)d_ws;

    k_prep<<<640, 256, 0, stream>>>(fb, w1, w2, w3, w4, wi, wf, wg, wo, ui, uf, ug, uo, wsu);
    k_all<<<BATCH / 16, 512, 0, stream>>>(audio, wsu, hin, cin, b1, b2, b3, b4,
                                          bxi, bxf, bxg, bxo, bhi, bhf, bhg, bho,
                                          cw, cb, out);
}

// Round 12
// 172.271 us; speedup vs baseline: 1.1395x; 1.1395x over previous
//
#include <hip/hip_runtime.h>
#include <math.h>

#define BATCH 8192
typedef unsigned short u16;
typedef unsigned int u32;
typedef __attribute__((ext_vector_type(8))) short bf16x8;
typedef __attribute__((ext_vector_type(4))) float f32x4;
typedef __attribute__((ext_vector_type(4))) unsigned short u16x4;

__device__ __forceinline__ float sigm(float v) { return 1.0f / (1.0f + __expf(-v)); }
__device__ __forceinline__ u16 f2bf(float f) {
    union { float f; u32 u; } v; v.f = f;
    u32 r = v.u + 0x7FFFu + ((v.u >> 16) & 1u);   // RNE
    return (u16)(r >> 16);
}
__device__ __forceinline__ float bf2f(u16 h) {
    union { u32 u; float f; } v; v.u = ((u32)h) << 16; return v.f;
}
__device__ __forceinline__ void split_store4(float4 v, u16* hp, u16* lp) {
    u16 h0 = f2bf(v.x), h1 = f2bf(v.y), h2 = f2bf(v.z), h3 = f2bf(v.w);
    u16x4 hv = {h0, h1, h2, h3};
    u16x4 lv = {f2bf(v.x - bf2f(h0)), f2bf(v.y - bf2f(h1)),
                f2bf(v.z - bf2f(h2)), f2bf(v.w - bf2f(h3))};
    *(u16x4*)hp = hv; *(u16x4*)lp = lv;
}
// fragment-linear B: element [(nt*nch + ch)*64 + lane]*8 + e  ==  B[nt*16+(lane&15)][ch*32+(lane>>4)*8+e]
__device__ __forceinline__ bf16x8 bfrag(const u16* Bf, int nt, int ch, int nch, int lane) {
    return *(const bf16x8*)(Bf + (((size_t)nt * nch + ch) * 64 + lane) * 8);
}
#define MFMA(a, b, c) __builtin_amdgcn_mfma_f32_16x16x32_bf16(a, b, c, 0, 0, 0)

// ---------------- workspace layout (u16 elements); hi plane then lo plane ----------------
#define S_FBT 69632   // [17 nt][8 ch] frag-linear, n<272, k<256
#define S_B1  61440   // 3 taps x [8 nt][5 ch], n<128, k<160 (k>=129 zero)
#define S_B2A 16384   // [4 nt][8 ch]
#define S_B2B 24576   // [4 nt][12 ch]
#define S_B3  8192    // [4 nt][4 ch]
#define S_B4  8192    // [8 nt][2 ch]
#define S_BL  131072  // [32 nt][8 ch]  n = gate*128+j, k: 0..127 W / 128..255 U
#define P_FBT 0
#define P_B1  139264
#define P_B2A 262144
#define P_B2B 294912
#define P_B3  344064
#define P_B4  360448
#define P_BL  376832
#define N_PREP 319488

// ---------------- k_prep: build fragment-linear split-bf16 B planes ----------------
__global__ __launch_bounds__(256) void k_prep(const float* __restrict__ fb,
                                              const float* __restrict__ w1, const float* __restrict__ w2,
                                              const float* __restrict__ w3, const float* __restrict__ w4,
                                              const float* __restrict__ wi, const float* __restrict__ wf,
                                              const float* __restrict__ wg, const float* __restrict__ wo,
                                              const float* __restrict__ ui, const float* __restrict__ uf,
                                              const float* __restrict__ ug, const float* __restrict__ uo,
                                              u16* __restrict__ wsu) {
    const float* Ws[8] = {wi, wf, wg, wo, ui, uf, ug, uo};
    for (int i = blockIdx.x * 256 + threadIdx.x; i < N_PREP; i += gridDim.x * 256) {
        int r = i;
        float v; int P, S, idx;
        if (r < S_FBT) {                                    // FBT nch=8
            int f = r >> 9, lane = (r & 511) >> 3, e = r & 7;
            int n = (f >> 3) * 16 + (lane & 15), k = (f & 7) * 32 + (lane >> 4) * 8 + e;
            int c = n >> 1, part = n & 1;
            v = (n < 258) ? fb[(size_t)(c + part * 129) * 256 + k] : 0.f;
            P = P_FBT; S = S_FBT; idx = r;
        } else if ((r -= S_FBT) < S_B1) {                   // B1: 3 taps, nch=5
            int kk = r / 20480, r2 = r - kk * 20480;
            int f = r2 >> 9, lane = (r2 & 511) >> 3, e = r2 & 7;
            int n = (f / 5) * 16 + (lane & 15), k = (f % 5) * 32 + (lane >> 4) * 8 + e;
            v = (k < 129) ? w1[(size_t)n * 387 + k * 3 + kk] : 0.f;
            P = P_B1; S = S_B1; idx = r;
        } else if ((r -= S_B1) < S_B2A) {                   // B2A nch=8
            int f = r >> 9, lane = (r & 511) >> 3, e = r & 7;
            int n = (f >> 3) * 16 + (lane & 15), k = (f & 7) * 32 + (lane >> 4) * 8 + e;
            v = w2[(size_t)n * 384 + (k & 127) * 3 + (k >> 7) + 1];
            P = P_B2A; S = S_B2A; idx = r;
        } else if ((r -= S_B2A) < S_B2B) {                  // B2B nch=12
            int f = r >> 9, lane = (r & 511) >> 3, e = r & 7;
            int n = (f / 12) * 16 + (lane & 15), k = (f % 12) * 32 + (lane >> 4) * 8 + e;
            v = w2[(size_t)n * 384 + (k & 127) * 3 + (k >> 7)];
            P = P_B2B; S = S_B2B; idx = r;
        } else if ((r -= S_B2B) < S_B3) {                   // B3 nch=4
            int f = r >> 9, lane = (r & 511) >> 3, e = r & 7;
            int n = (f >> 2) * 16 + (lane & 15), k = (f & 3) * 32 + (lane >> 4) * 8 + e;
            v = w3[(size_t)n * 192 + (k & 63) * 3 + (k >> 6) + 1];
            P = P_B3; S = S_B3; idx = r;
        } else if ((r -= S_B3) < S_B4) {                    // B4 nch=2
            int f = r >> 9, lane = (r & 511) >> 3, e = r & 7;
            int n = (f >> 1) * 16 + (lane & 15), k = (f & 1) * 32 + (lane >> 4) * 8 + e;
            v = w4[(size_t)n * 192 + k * 3 + 1];
            P = P_B4; S = S_B4; idx = r;
        } else {                                            // BL nch=8
            r -= S_B4;
            int f = r >> 9, lane = (r & 511) >> 3, e = r & 7;
            int n = (f >> 3) * 16 + (lane & 15), k = (f & 7) * 32 + (lane >> 4) * 8 + e;
            int g = n >> 7, j = n & 127;
            v = Ws[g + ((k >= 128) ? 4 : 0)][(size_t)j * 128 + (k & 127)];
            P = P_BL; S = S_BL; idx = r;
        }
        u16 h = f2bf(v);
        wsu[P + idx] = h;
        wsu[P + S + idx] = f2bf(v - bf2f(h));
    }
}

// ---------------- k_all: STFT -> mag -> enc1 -> enc2 -> enc3 -> enc4 -> LSTM -> head ----------------
// block 512 (8 waves), 16 batches (64 stft rows, mt=4), grid 512 (= 2 blocks/CU).
// LDS union (u16), time-multiplexed (R9 structure; mag stride 168 -> 136, conflict-free class):
//   phase A: audio  aAh[0,11520) aAl[11520,23040)   stride 720 (conflict-free)
//   phase B: mag    mAh[0,13080) mAl[13080,26160)   rows bb*6+tp, stride 136 (+24 pad/plane)
//   phase C: e1     eAh[0,8320)  eAl[8320,16640)    rows=batch, stride 520
//            s2 [16640,20992) s3 [20992,23296) xh [23296,31744) pr [31744,32256)
__global__ __launch_bounds__(512) void k_all(const float* __restrict__ audio,
                                             const u16* __restrict__ wsu,
                                             const float* __restrict__ hin, const float* __restrict__ cin,
                                             const float* __restrict__ b1, const float* __restrict__ b2,
                                             const float* __restrict__ b3, const float* __restrict__ b4,
                                             const float* __restrict__ bxi, const float* __restrict__ bxf,
                                             const float* __restrict__ bxg, const float* __restrict__ bxo,
                                             const float* __restrict__ bhi, const float* __restrict__ bhf,
                                             const float* __restrict__ bhg, const float* __restrict__ bho,
                                             const float* __restrict__ cw, const float* __restrict__ cb,
                                             float* __restrict__ out) {
    __shared__ __align__(16) u16 uni[32256];
    u16* aAh = uni;
    u16* aAl = uni + 11520;
    u16* mAh = uni;
    u16* mAl = uni + 13080;
    u16* eAh = uni;
    u16* eAl = uni + 8320;
    u16* s2h = uni + 16640;
    u16* s2l = uni + 18816;
    u16* s3h = uni + 20992;
    u16* s3l = uni + 22144;
    u16* xhh = uni + 23296;
    u16* xhl = uni + 27520;
    float* pr = (float*)(uni + 31744);
    const int tid = threadIdx.x;
    const int b0 = blockIdx.x << 4;
    // ---- phase A: stage audio (split bf16, reflect pad) ----
    for (int i = tid; i < 16 * 160; i += 512) {
        int bb = i / 160, j4 = (i - bb * 160) * 4;
        const float* ap = audio + (size_t)(b0 + bb) * 576;
        float4 v;
        if (j4 < 576) v = *(const float4*)(ap + j4);
        else { v.x = ap[1150 - j4]; v.y = ap[1149 - j4]; v.z = ap[1148 - j4]; v.w = ap[1147 - j4]; }
        int phys = bb * 720 + j4 + (j4 >> 7) * 8;
        split_store4(v, aAh + phys, aAl + phys);
    }
    __syncthreads();
    const int lane = tid & 63, w = tid >> 6;
    const int m = lane & 15, quad = lane >> 4;
    // ---- GEMM1 (STFT): wave w owns nt = 2w..2w+1 (w==7 also nt=16), mt=4 ----
    const u16* fbT = wsu + P_FBT;
    const int tcnt = (w == 7) ? 3 : 2;
    f32x4 acc[4][3];
    #pragma unroll
    for (int mt = 0; mt < 4; ++mt)
        #pragma unroll
        for (int t = 0; t < 3; ++t) acc[mt][t] = (f32x4){0.f, 0.f, 0.f, 0.f};
    for (int ch = 0; ch < 8; ++ch) {
        bf16x8 ah[4], al[4];
        #pragma unroll
        for (int mt = 0; mt < 4; ++mt) {
            int Rm = mt * 16 + m;
            int phys = (Rm >> 2) * 720 + (Rm & 3) * 136 + ch * 32 + quad * 8 + ((ch >= 4) ? 8 : 0);
            ah[mt] = *(const bf16x8*)(aAh + phys);
            al[mt] = *(const bf16x8*)(aAl + phys);
        }
        #pragma unroll
        for (int tt = 0; tt < 3; ++tt) {
            if (tt < tcnt) {
                int t = w * 2 + tt;
                bf16x8 bh = bfrag(fbT, t, ch, 8, lane);
                bf16x8 bl_ = bfrag(fbT + S_FBT, t, ch, 8, lane);
                #pragma unroll
                for (int mt = 0; mt < 4; ++mt) {
                    acc[mt][tt] = MFMA(ah[mt], bh, acc[mt][tt]);
                    acc[mt][tt] = MFMA(ah[mt], bl_, acc[mt][tt]);
                    acc[mt][tt] = MFMA(al[mt], bh, acc[mt][tt]);
                }
            }
        }
    }
    __syncthreads();                                // audio dead
    for (int i = tid; i < 13080; i += 512) ((u32*)uni)[i] = 0u;   // zero both mag planes (26160 u16)
    __syncthreads();
    // ---- magnitude epilogue -> mag LDS (6-row layout, stride 136, boundary rows stay zero) ----
    #pragma unroll
    for (int tt = 0; tt < 3; ++tt) {
        if (tt < tcnt) {
            int n = (w * 2 + tt) * 16 + m;
            #pragma unroll
            for (int mt = 0; mt < 4; ++mt)
                #pragma unroll
                for (int r = 0; r < 4; ++r) {
                    float vv = acc[mt][tt][r];
                    float s = vv * vv;
                    s += __shfl_xor(s, 1);
                    if (!(n & 1)) {
                        int R = mt * 16 + quad * 4 + r;
                        int bb = R >> 2, t = R & 3, c = n >> 1;
                        float sv = sqrtf(s);
                        u16 h = f2bf(sv);
                        int phys = (bb * 6 + t + 1) * 136 + c;
                        mAh[phys] = h;
                        mAl[phys] = f2bf(sv - bf2f(h));
                    }
                }
        }
    }
    __syncthreads();
    // ---- GEMM2 (enc1): wave w owns nt = w (N=128), mt=4, K = 3 taps x 5 ch ----
    // ch=4 quad>=1 fragments alias next row's finite data; B1 weights are zero for k>=129 -> contributes 0
    const u16* B1h = wsu + P_B1;
    const u16* B1l = wsu + P_B1 + S_B1;
    f32x4 acc2[4];
    #pragma unroll
    for (int mt = 0; mt < 4; ++mt) acc2[mt] = (f32x4){0.f, 0.f, 0.f, 0.f};
    #pragma unroll
    for (int kk = 0; kk < 3; ++kk) {
        #pragma unroll
        for (int ch = 0; ch < 5; ++ch) {
            bf16x8 bh = bfrag(B1h + kk * 20480, w, ch, 5, lane);
            bf16x8 bl_ = bfrag(B1l + kk * 20480, w, ch, 5, lane);
            #pragma unroll
            for (int mt = 0; mt < 4; ++mt) {
                int Rm = mt * 16 + m;
                int phys = ((Rm >> 2) * 6 + (Rm & 3) + kk) * 136 + ch * 32 + quad * 8;
                bf16x8 ah = *(const bf16x8*)(mAh + phys);
                bf16x8 al = *(const bf16x8*)(mAl + phys);
                acc2[mt] = MFMA(ah, bh, acc2[mt]);
                acc2[mt] = MFMA(ah, bl_, acc2[mt]);
                acc2[mt] = MFMA(al, bh, acc2[mt]);
            }
        }
    }
    __syncthreads();                                // mag dead
    // ---- e1 -> LDS (split), h -> xh cols 128..255 ----
    {
        int n = w * 16 + m;
        float bv = b1[n];
        #pragma unroll
        for (int mt = 0; mt < 4; ++mt)
            #pragma unroll
            for (int r = 0; r < 4; ++r) {
                int R = mt * 16 + quad * 4 + r;
                float vv = fmaxf(acc2[mt][r] + bv, 0.f);
                u16 h = f2bf(vv);
                int phys = (R >> 2) * 520 + (R & 3) * 128 + n;
                eAh[phys] = h;
                eAl[phys] = f2bf(vv - bf2f(h));
            }
    }
    for (int i = tid; i < 16 * 32; i += 512) {
        int row = i >> 5, c4 = (i & 31) * 4;
        float4 v = *(const float4*)(hin + (size_t)(b0 + row) * 128 + c4);
        split_store4(v, xhh + row * 264 + 128 + c4, xhl + row * 264 + 128 + c4);
    }
    __syncthreads();
    // ---- enc2: waves 0-3 = enc2a (K=256), waves 4-7 = enc2b (K=384) ----
    {
        const int isB = w >> 2, nt = w & 3;
        const int awoff = isB ? 128 : 0;
        const int nch = isB ? 12 : 8;
        const u16* Bh = wsu + (isB ? P_B2B : P_B2A);
        const u16* Bl = Bh + (isB ? S_B2B : S_B2A);
        f32x4 a2 = (f32x4){0.f, 0.f, 0.f, 0.f};
        for (int ch = 0; ch < nch; ++ch) {
            int phys = m * 520 + awoff + ch * 32 + quad * 8;
            bf16x8 ah = *(const bf16x8*)(eAh + phys);
            bf16x8 al = *(const bf16x8*)(eAl + phys);
            bf16x8 bh = bfrag(Bh, nt, ch, nch, lane);
            bf16x8 bl_ = bfrag(Bl, nt, ch, nch, lane);
            a2 = MFMA(ah, bh, a2);
            a2 = MFMA(ah, bl_, a2);
            a2 = MFMA(al, bh, a2);
        }
        const int oc = nt * 16 + m;
        const float bv = b2[oc];
        const int col = isB * 64 + oc;
        #pragma unroll
        for (int r = 0; r < 4; ++r) {
            int row = quad * 4 + r;
            float vv = fmaxf(a2[r] + bv, 0.f);
            u16 h = f2bf(vv);
            s2h[row * 136 + col] = h;
            s2l[row * 136 + col] = f2bf(vv - bf2f(h));
        }
    }
    __syncthreads();
    // ---- enc3: waves 0-3, K=128 (4 ch), N=64 ----
    if (w < 4) {
        const u16* Bh = wsu + P_B3;
        const u16* Bl = Bh + S_B3;
        f32x4 a3 = (f32x4){0.f, 0.f, 0.f, 0.f};
        #pragma unroll
        for (int ch = 0; ch < 4; ++ch) {
            int phys = m * 136 + ch * 32 + quad * 8;
            bf16x8 ah = *(const bf16x8*)(s2h + phys);
            bf16x8 al = *(const bf16x8*)(s2l + phys);
            bf16x8 bh = bfrag(Bh, w, ch, 4, lane);
            bf16x8 bl_ = bfrag(Bl, w, ch, 4, lane);
            a3 = MFMA(ah, bh, a3);
            a3 = MFMA(ah, bl_, a3);
            a3 = MFMA(al, bh, a3);
        }
        const int n = w * 16 + m;
        const float bv = b3[n];
        #pragma unroll
        for (int r = 0; r < 4; ++r) {
            int row = quad * 4 + r;
            float vv = fmaxf(a3[r] + bv, 0.f);
            u16 h = f2bf(vv);
            s3h[row * 72 + n] = h;
            s3l[row * 72 + n] = f2bf(vv - bf2f(h));
        }
    }
    __syncthreads();
    // ---- enc4: all 8 waves, K=64 (2 ch), N=128 -> x into xh cols 0..127 ----
    {
        const u16* Bh = wsu + P_B4;
        const u16* Bl = Bh + S_B4;
        f32x4 a4 = (f32x4){0.f, 0.f, 0.f, 0.f};
        #pragma unroll
        for (int ch = 0; ch < 2; ++ch) {
            int phys = m * 72 + ch * 32 + quad * 8;
            bf16x8 ah = *(const bf16x8*)(s3h + phys);
            bf16x8 al = *(const bf16x8*)(s3l + phys);
            bf16x8 bh = bfrag(Bh, w, ch, 2, lane);
            bf16x8 bl_ = bfrag(Bl, w, ch, 2, lane);
            a4 = MFMA(ah, bh, a4);
            a4 = MFMA(ah, bl_, a4);
            a4 = MFMA(al, bh, a4);
        }
        const int n = w * 16 + m;
        const float bv = b4[n];
        #pragma unroll
        for (int r = 0; r < 4; ++r) {
            int row = quad * 4 + r;
            float vv = fmaxf(a4[r] + bv, 0.f);
            u16 h = f2bf(vv);
            xhh[row * 264 + n] = h;
            xhl[row * 264 + n] = f2bf(vv - bf2f(h));
        }
    }
    __syncthreads();
    // ---- LSTM: wave w owns j-tile w x all 4 gates; K=256 (8 ch) ----
    {
        const u16* BLh = wsu + P_BL;
        const u16* BLl = BLh + S_BL;
        f32x4 ag[4];
        #pragma unroll
        for (int g = 0; g < 4; ++g) ag[g] = (f32x4){0.f, 0.f, 0.f, 0.f};
        #pragma unroll 2
        for (int ch = 0; ch < 8; ++ch) {
            int phys = m * 264 + ch * 32 + quad * 8;
            bf16x8 ah = *(const bf16x8*)(xhh + phys);
            bf16x8 al = *(const bf16x8*)(xhl + phys);
            #pragma unroll
            for (int g = 0; g < 4; ++g) {
                int nt = g * 8 + w;
                bf16x8 bh = bfrag(BLh, nt, ch, 8, lane);
                bf16x8 bl_ = bfrag(BLl, nt, ch, 8, lane);
                ag[g] = MFMA(ah, bh, ag[g]);
                ag[g] = MFMA(ah, bl_, ag[g]);
                ag[g] = MFMA(al, bh, ag[g]);
            }
        }
        float partial[4];
        const int j = w * 16 + m;
        const float bi = bxi[j] + bhi[j];
        const float bff = bxf[j] + bhf[j];
        const float bgg = bxg[j] + bhg[j];
        const float boo = bxo[j] + bho[j];
        const float cwj = cw[j];
        #pragma unroll
        for (int r = 0; r < 4; ++r) {
            const int b = b0 + quad * 4 + r;
            const float ig = sigm(ag[0][r] + bi);
            const float fg = sigm(ag[1][r] + bff);
            const float gg = tanhf(ag[2][r] + bgg);
            const float og = sigm(ag[3][r] + boo);
            const float ci = cin[(size_t)b * 128 + j];
            const float co = fg * ci + ig * gg;
            const float ho = og * tanhf(co);
            out[(size_t)BATCH + (size_t)b * 128 + j] = ho;
            out[(size_t)BATCH + (size_t)BATCH * 128 + (size_t)b * 128 + j] = co;
            partial[r] = fmaxf(ho, 0.f) * cwj;
        }
        #pragma unroll
        for (int off = 1; off < 16; off <<= 1)
            #pragma unroll
            for (int r = 0; r < 4; ++r) partial[r] += __shfl_xor(partial[r], off);
        if (m == 0) {
            #pragma unroll
            for (int r = 0; r < 4; ++r) pr[w * 16 + quad * 4 + r] = partial[r];
        }
    }
    __syncthreads();
    if (tid < 16) {
        float s = cb[0];
        #pragma unroll
        for (int g = 0; g < 8; ++g) s += pr[g * 16 + tid];
        out[b0 + tid] = sigm(s);
    }
}

extern "C" void kernel_launch(void* const* d_in, const int* in_sizes, int n_in,
                              void* d_out, int out_size, void* d_ws, size_t ws_size,
                              hipStream_t stream) {
    const float* audio = (const float*)d_in[0];
    const float* hin   = (const float*)d_in[1];
    const float* cin   = (const float*)d_in[2];
    const float* fb    = (const float*)d_in[3];
    const float* w1    = (const float*)d_in[4];
    const float* b1    = (const float*)d_in[5];
    const float* w2    = (const float*)d_in[6];
    const float* b2    = (const float*)d_in[7];
    const float* w3    = (const float*)d_in[8];
    const float* b3    = (const float*)d_in[9];
    const float* w4    = (const float*)d_in[10];
    const float* b4    = (const float*)d_in[11];
    const float* wi    = (const float*)d_in[12];
    const float* wf    = (const float*)d_in[13];
    const float* wg    = (const float*)d_in[14];
    const float* wo    = (const float*)d_in[15];
    const float* ui    = (const float*)d_in[16];
    const float* uf    = (const float*)d_in[17];
    const float* ug    = (const float*)d_in[18];
    const float* uo    = (const float*)d_in[19];
    const float* bxi   = (const float*)d_in[20];
    const float* bxf   = (const float*)d_in[21];
    const float* bxg   = (const float*)d_in[22];
    const float* bxo   = (const float*)d_in[23];
    const float* bhi   = (const float*)d_in[24];
    const float* bhf   = (const float*)d_in[25];
    const float* bhg   = (const float*)d_in[26];
    const float* bho   = (const float*)d_in[27];
    const float* cw    = (const float*)d_in[28];
    const float* cb    = (const float*)d_in[29];
    float* out = (float*)d_out;

    u16* wsu = (u16*)d_ws;

    k_prep<<<640, 256, 0, stream>>>(fb, w1, w2, w3, w4, wi, wf, wg, wo, ui, uf, ug, uo, wsu);
    k_all<<<BATCH / 16, 512, 0, stream>>>(audio, wsu, hin, cin, b1, b2, b3, b4,
                                          bxi, bxf, bxg, bxo, bhi, bhf, bhg, bho,
                                          cw, cb, out);
}